// Round 10
// baseline (148.501 us; speedup 1.0000x reference)
//
#include <hip/hip_runtime.h>
#include <hip/hip_bf16.h>
#include <stdint.h>

// GAT layer, MI355X. B=32, N=512, Fin=256, F=64, H=8. fp32 in / fp32 out.
// R15 = R14 (k1 fixed: k0+k1 ~20us; k2 regressed to 52us = the whole kernel)
// + k2-internal rework only:
//   1. hT ws layout -> [2 halves][64][264]; k2 issues half-1 global loads to
//      REGISTERS first (T14 issue-early), stages half-0, barrier, computes
//      ks 0..7, writes half-1, barrier, computes ks 8..15. Staging latency
//      hides under compute instead of serializing at block start.
//   2. P-gen on float2 so hipcc can emit v_pk_add_f32/v_pk_mul_f32
//      (VALUBusy 34% = 18us P-gen floor; packing cuts add/mul in half).
// k0_all, k1 (except 2-line hT index), fallback: byte-identical to R14.
// Diagnostic: k2 VGPR ~75 => h1 prefetch kept; ~52 => compiler sank it (R13
// failure mode) and the staging-overlap never happened.
// Fallback: if ws_size < 28MB, launch the proven R8 fused kernel.

#define ALPHA  0.2f
#define ESCALE 1.4426950408889634f   // log2(e), folded into a at stage 0

typedef __bf16 bf16x8 __attribute__((ext_vector_type(8)));
typedef __bf16 bf16x4 __attribute__((ext_vector_type(4)));
typedef float  f32x4  __attribute__((ext_vector_type(4)));
typedef float  f32x2  __attribute__((ext_vector_type(2)));

#if __has_builtin(__builtin_amdgcn_exp2f)
#define EXP2(x) __builtin_amdgcn_exp2f(x)
#else
#define EXP2(x) exp2f(x)
#endif

#define HT_STRIDE 520   // fused-fallback only
#define WT_STRIDE 264   // fused-fallback only
#define HROW 264        // k2 half-row stride: 256 + 8 pad (528B, 33 granules)

__device__ inline bf16x8 ld8(const float* p) {
    float4 a0 = *(const float4*)p;
    float4 a1 = *(const float4*)(p + 4);
    bf16x8 r;
    r[0]=(__bf16)a0.x; r[1]=(__bf16)a0.y; r[2]=(__bf16)a0.z; r[3]=(__bf16)a0.w;
    r[4]=(__bf16)a1.x; r[5]=(__bf16)a1.y; r[6]=(__bf16)a1.z; r[7]=(__bf16)a1.w;
    return r;
}

// ---------------- k0_all: pre-format pass (unchanged from R14) -------------
__global__ __launch_bounds__(512) void k0_all(const float* __restrict__ x,
                                              const float* __restrict__ W,
                                              const float* __restrict__ adj,
                                              __bf16* __restrict__ xbf,
                                              __bf16* __restrict__ Wbf,
                                              unsigned* __restrict__ mask) {
    __shared__ float tile[64][65];
    const int blk = blockIdx.x, tid = threadIdx.x;
    if (blk < 1024) {
        long c = (long)blk * 512 + tid;          // 0..524287
        int s  = (int)(c & 7);
        int r  = (int)((c >> 3) & 511);
        int kc = (int)((c >> 12) & 3);
        int b  = (int)(c >> 14);
        const float* src = x + (((long)b * 512 + r) * 256 + kc * 64 + s * 8);
        float4 a0 = *(const float4*)src;
        float4 a1 = *(const float4*)(src + 4);
        bf16x8 o;
        o[0]=(__bf16)a0.x; o[1]=(__bf16)a0.y; o[2]=(__bf16)a0.z; o[3]=(__bf16)a0.w;
        o[4]=(__bf16)a1.x; o[5]=(__bf16)a1.y; o[6]=(__bf16)a1.z; o[7]=(__bf16)a1.w;
        *(bf16x8*)(xbf + c * 8) = o;
    } else if (blk < 1056) {
        int bi = blk - 1024;
        int kt = bi & 3, ft = bi >> 2;
        int ff = tid & 63;
        #pragma unroll
        for (int i = 0; i < 8; ++i) {
            int kk = (tid >> 6) + i * 8;
            tile[kk][ff] = W[(long)(kt * 64 + kk) * 512 + ft * 64 + ff];
        }
        __syncthreads();
        int kk2 = tid & 63;
        #pragma unroll
        for (int i = 0; i < 8; ++i) {
            int ff2 = (tid >> 6) + i * 8;
            Wbf[(long)(ft * 64 + ff2) * 256 + kt * 64 + kk2] = (__bf16)tile[kk2][ff2];
        }
    } else {
        const int T2 = (blk - 1056) * 512 + tid;
        const int w    = T2 & 3;
        const int quad = (T2 >> 2) & 3;
        const int row  = (T2 >> 4) & 511;
        const int b    = T2 >> 13;
        const float* p = adj + ((long)b * 512 + row) * 512 + quad * 8;
        unsigned word = 0;
        #pragma unroll
        for (int k = 0; k < 4; ++k) {
            const float* qp = p + (w * 4 + k) * 32;
            float4 a0 = *(const float4*)qp;
            float4 a1 = *(const float4*)(qp + 4);
            unsigned byte =  (a0.x > 0.f ? 1u : 0u)
                          | ((a0.y > 0.f ? 1u : 0u) << 1)
                          | ((a0.z > 0.f ? 1u : 0u) << 2)
                          | ((a0.w > 0.f ? 1u : 0u) << 3)
                          | ((a1.x > 0.f ? 1u : 0u) << 4)
                          | ((a1.y > 0.f ? 1u : 0u) << 5)
                          | ((a1.z > 0.f ? 1u : 0u) << 6)
                          | ((a1.w > 0.f ? 1u : 0u) << 7);
            word |= byte << (8 * k);
        }
        mask[T2] = word;
    }
}

// ---------------- k1 v4: LDS-only inner loop (R14, hT index updated) -------
struct SmemK1 {
    __bf16 Wt[64 * 256];            // 32,768 B, granule-swizzled
    __bf16 Xt[256 * 64];            // 32,768 B, granule-swizzled
    float  asrc[64], adst[64];      //    512 B
};                                  // 66,048 B -> 2 blocks/CU

__global__ __launch_bounds__(512, 4) void k1_gemm(const __bf16* __restrict__ xbf,
                                                  const __bf16* __restrict__ Wbf,
                                                  const float* __restrict__ a,
                                                  __bf16* __restrict__ hT,
                                                  float* __restrict__ ssrc,
                                                  float* __restrict__ sdst) {
    __shared__ SmemK1 sm;
    const int b = blockIdx.x, h = blockIdx.y, zz = blockIdx.z; // XCD = b%8
    const int tid  = threadIdx.x;                // 512 thr, 8 waves
    const int wave = tid >> 6, lane = tid & 63;
    const int quad = lane >> 4, col = lane & 15;
    const int row0 = zz * 256;                   // block's 256 rows

    if (tid < 128) {
        float v = a[h * 128 + tid] * ESCALE;
        if (tid < 64) sm.asrc[tid] = v; else sm.adst[tid - 64] = v;
    }
    {   // Wt stage: linear coalesced read, XOR-swz write
        const uint4* src = (const uint4*)(Wbf + (long)h * 64 * 256);
        #pragma unroll
        for (int i = 0; i < 4; ++i) {
            int c = tid + i * 512;
            int f = c >> 5, s = c & 31;
            int sw = (s & 24) | ((s & 7) ^ (f & 7));
            *(uint4*)((char*)sm.Wt + f * 512 + sw * 16) = src[c];
        }
    }
    {   // Xt stage kc=0: contiguous 32KB slab
        const uint4* src = (const uint4*)(xbf + (((long)b * 4 + 0) * 512 + row0) * 64);
        #pragma unroll
        for (int i = 0; i < 4; ++i) {
            int c = tid + i * 512;
            int r = c >> 3, s = c & 7;
            *(uint4*)((char*)sm.Xt + r * 128 + ((s ^ (r & 7)) * 16)) = src[c];
        }
    }
    __syncthreads();

    f32x4 acc[2][4] = {};
    #pragma unroll
    for (int kc = 0; kc < 4; ++kc) {             // K = 256, 4 chunks of 64
        #pragma unroll
        for (int sk = 0; sk < 2; ++sk) {
            bf16x8 av[2], bv[4];
            #pragma unroll
            for (int it = 0; it < 2; ++it) {
                int r = wave * 32 + it * 16 + col;
                int g = (sk * 4 + quad) ^ (r & 7);
                av[it] = *(const bf16x8*)((const char*)sm.Xt + r * 128 + g * 16);
            }
            #pragma unroll
            for (int nt = 0; nt < 4; ++nt) {
                int n = nt * 16 + col;
                int G = kc * 8 + sk * 4 + quad;
                int Gs = (G & 24) | ((G & 7) ^ (n & 7));
                bv[nt] = *(const bf16x8*)((const char*)sm.Wt + n * 512 + Gs * 16);
            }
            #pragma unroll
            for (int it = 0; it < 2; ++it)
                #pragma unroll
                for (int nt = 0; nt < 4; ++nt)
                    acc[it][nt] = __builtin_amdgcn_mfma_f32_16x16x32_bf16(av[it], bv[nt], acc[it][nt], 0, 0, 0);
        }
        if (kc < 3) {                            // restage Xt for kc+1
            __syncthreads();
            const uint4* src = (const uint4*)(xbf + (((long)b * 4 + kc + 1) * 512 + row0) * 64);
            #pragma unroll
            for (int i = 0; i < 4; ++i) {
                int c = tid + i * 512;
                int r = c >> 3, s = c & 7;
                *(uint4*)((char*)sm.Xt + r * 128 + ((s ^ (r & 7)) * 16)) = src[c];
            }
            __syncthreads();
        }
    }

    // epilogue: hT in HALF-TILED layout [2][64][HROW] per (b,h)
    const long bh = (long)b * 8 + h;
    __bf16* hTb = hT + bh * (2 * 64 * HROW);
    {
        #pragma unroll
        for (int it = 0; it < 2; ++it)
            #pragma unroll
            for (int nt = 0; nt < 4; ++nt) {
                int f = nt * 16 + col;
                int j = row0 + wave * 32 + it * 16 + quad * 4;
                int half = j >> 8, jj = j & 255;
                bf16x4 pk = { (__bf16)acc[it][nt][0], (__bf16)acc[it][nt][1],
                              (__bf16)acc[it][nt][2], (__bf16)acc[it][nt][3] };
                *(bf16x4*)(hTb + (half * 64 + f) * HROW + jj) = pk;
            }
    }
    {
        float asr[4], adr[4];
        #pragma unroll
        for (int nt = 0; nt < 4; ++nt) {
            asr[nt] = sm.asrc[nt * 16 + col];
            adr[nt] = sm.adst[nt * 16 + col];
        }
        #pragma unroll
        for (int it = 0; it < 2; ++it)
            #pragma unroll
            for (int r = 0; r < 4; ++r) {
                float ps = 0.f, pd = 0.f;
                #pragma unroll
                for (int nt = 0; nt < 4; ++nt) {
                    ps += acc[it][nt][r] * asr[nt];
                    pd += acc[it][nt][r] * adr[nt];
                }
                #pragma unroll
                for (int m = 1; m <= 8; m <<= 1) {   // stays within quad
                    ps += __shfl_xor(ps, m, 64);
                    pd += __shfl_xor(pd, m, 64);
                }
                if (col == 0) {
                    int j = row0 + wave * 32 + it * 16 + quad * 4 + r;
                    ssrc[bh * 512 + j] = ps;
                    sdst[bh * 512 + j] = pd;
                }
            }
    }
}

// ---------------- k2 v3: half-overlapped staging + packed P-gen ------------
struct SmemK2 {
    __bf16 hTh[2][64][HROW];        // 67,584 B (two 33,792B halves)
    float  sds[512];                //  2,048 B
};                                  // 69,632 B -> 2 blocks/CU

// one attention K-step on a given staged half (HF = ks>>3 at call site)
#define K2STEP(KS, HF)                                                         \
    {                                                                          \
        const int j0  = (KS) * 32 + quad * 8;    /* sds index (global j) */    \
        const int jj0 = ((KS) & 7) * 32 + quad * 8; /* within-half j   */      \
        f32x4 s0 = *(const f32x4*)&sm.sds[j0];                                 \
        f32x4 s1 = *(const f32x4*)&sm.sds[j0 + 4];                             \
        f32x2 sp[4] = { {s0[0],s0[1]}, {s0[2],s0[3]},                          \
                        {s1[0],s1[1]}, {s1[2],s1[3]} };                        \
        unsigned mb[2];                                                        \
        _Pragma("unroll")                                                      \
        for (int it = 0; it < 2; ++it) {                                       \
            unsigned wrd = ((KS) < 4) ? mk[it].x : ((KS) < 8) ? mk[it].y       \
                         : ((KS) < 12) ? mk[it].z : mk[it].w;                  \
            mb[it] = (wrd >> (((KS) & 3) * 8)) & 0xFFu;                        \
        }                                                                      \
        bf16x8 P[2];                                                           \
        _Pragma("unroll")                                                      \
        for (int it = 0; it < 2; ++it) {                                       \
            f32x2 siv = { si[it], si[it] };                                    \
            _Pragma("unroll")                                                  \
            for (int p = 0; p < 4; ++p) {        /* packed add/mul */          \
                f32x2 e  = sp[p] + siv;          /* v_pk_add_f32 */            \
                f32x2 ea = e * ALPHA;            /* v_pk_mul_f32 */            \
                float l0 = fmaxf(e[0], ea[0]);                                 \
                float l1 = fmaxf(e[1], ea[1]);                                 \
                float x0 = EXP2(l0), x1 = EXP2(l1);                            \
                P[it][2*p]   = (__bf16)(((mb[it] >> (2*p))   & 1u) ? x0 : 0.f);\
                P[it][2*p+1] = (__bf16)(((mb[it] >> (2*p+1)) & 1u) ? x1 : 0.f);\
            }                                                                  \
        }                                                                      \
        bf16x8 bv[4];                                                          \
        _Pragma("unroll")                                                      \
        for (int nt = 0; nt < 4; ++nt)                                         \
            bv[nt] = *(const bf16x8*)(&sm.hTh[HF][nt * 16 + col][jj0]);        \
        _Pragma("unroll")                                                      \
        for (int it = 0; it < 2; ++it) {                                       \
            _Pragma("unroll")                                                  \
            for (int nt = 0; nt < 4; ++nt)                                     \
                acc[it][nt] = __builtin_amdgcn_mfma_f32_16x16x32_bf16(P[it], bv[nt], acc[it][nt], 0, 0, 0); \
            accs[it] = __builtin_amdgcn_mfma_f32_16x16x32_bf16(P[it], ones, accs[it], 0, 0, 0); \
        }                                                                      \
    }

__global__ __launch_bounds__(512, 4) void k2_attn(const uint4* __restrict__ mask,
                                                  const __bf16* __restrict__ hT,
                                                  const float* __restrict__ ssrc,
                                                  const float* __restrict__ sdst,
                                                  float* __restrict__ out) {
    __shared__ SmemK2 sm;
    const int b = blockIdx.x, h = blockIdx.y, q = blockIdx.z;
    const int tid  = threadIdx.x;                // 512 thr, 8 waves
    const int wave = tid >> 6, lane = tid & 63;
    const int quad = lane >> 4, col = lane & 15;
    const long bh = (long)b * 8 + h;
    const int rowbase = q * 256 + wave * 32;     // wave owns 32 rows

    const __bf16* hTb = hT + bh * (2 * 64 * HROW);
    const uint4* srcH0 = (const uint4*)hTb;                    // 2112 chunks
    const uint4* srcH1 = (const uint4*)(hTb + 64 * HROW);      // 2112 chunks

    // T14 issue-early: half-1 loads into regs; they fly over half-0 staging
    // and the first compute phase. Consumed (ds_write) after phase 1.
    uint4 h1[4]; uint4 h1x = {};
    #pragma unroll
    for (int i = 0; i < 4; ++i) h1[i] = srcH1[tid + i * 512];
    if (tid < 64) h1x = srcH1[2048 + tid];

    {   // stage half-0 (linear, coalesced)
        uint4* dst = (uint4*)&sm.hTh[0][0][0];
        #pragma unroll
        for (int i = 0; i < 4; ++i) dst[tid + i * 512] = srcH0[tid + i * 512];
        if (tid < 64) dst[2048 + tid] = srcH0[2048 + tid];
    }
    sm.sds[tid] = sdst[bh * 512 + tid];

    float si[2]; uint4 mk[2];
    #pragma unroll
    for (int it = 0; it < 2; ++it) {
        int i = rowbase + it * 16 + col;         // A-row m = lane&15
        si[it] = ssrc[bh * 512 + i];
        mk[it] = mask[((long)b * 512 + i) * 4 + quad];
    }
    __syncthreads();                             // half-0 + sds ready

    bf16x8 ones;
    #pragma unroll
    for (int u = 0; u < 8; ++u) ones[u] = (__bf16)1.0f;

    f32x4 acc[2][4] = {};
    f32x4 accs[2]   = {};                        // row sums via P@ones

    #pragma unroll
    for (int ks = 0; ks < 8; ++ks)               // phase 1: half-0
        K2STEP(ks, 0)

    {   // write half-1 (regs -> LDS), then barrier
        uint4* dst = (uint4*)&sm.hTh[1][0][0];
        #pragma unroll
        for (int i = 0; i < 4; ++i) dst[tid + i * 512] = h1[i];
        if (tid < 64) dst[2048 + tid] = h1x;
    }
    __syncthreads();                             // half-1 ready

    #pragma unroll
    for (int ks = 8; ks < 16; ++ks)              // phase 2: half-1
        K2STEP(ks, 1)

    // epilogue: accs rows (quad*4+r) align with acc rows
    #pragma unroll
    for (int it = 0; it < 2; ++it)
        #pragma unroll
        for (int r = 0; r < 4; ++r) {
            float s = accs[it][r];
            float inv = (s > 0.f) ? 1.0f / s : 0.f;
            int i = rowbase + it * 16 + quad * 4 + r;
            float* orow = out + ((long)b * 512 + i) * 512 + h * 64;
            #pragma unroll
            for (int nt = 0; nt < 4; ++nt)
                orow[nt * 16 + col] = acc[it][nt][r] * inv;
        }
}

// ---------------- fallback: R8 fused kernel (proven) -----------------------
struct SmemF {
    __bf16 hT[64][HT_STRIDE];
    __bf16 WT[64][WT_STRIDE];
    float  ssrc[512], sdst[512];
    float  asrc[64], adst[64];
};

__global__ __launch_bounds__(1024, 4) void k_gat_fused(const float* __restrict__ x,
                                                       const float* __restrict__ adj,
                                                       const float* __restrict__ W,
                                                       const float* __restrict__ a,
                                                       float* __restrict__ out) {
    __shared__ SmemF sm;
    const int b = blockIdx.x, h = blockIdx.y;
    const int tid  = threadIdx.x;
    const int wave = tid >> 6, lane = tid & 63;
    const int quad = lane >> 4, col = lane & 15;

    if (tid < 128) {
        float v = a[h * 128 + tid] * ESCALE;
        if (tid < 64) sm.asrc[tid] = v; else sm.adst[tid - 64] = v;
    }
    {
        int c = tid & 63, k0 = tid >> 6;
        #pragma unroll 4
        for (int t = 0; t < 16; ++t)
            sm.WT[c][k0 + t * 16] = (__bf16)W[(long)(k0 + t * 16) * 512 + h * 64 + c];
    }
    __syncthreads();
    {
        const float* xb = x + (long)b * 512 * 256;
        f32x4 acc[2][4] = {};
        for (int ks = 0; ks < 8; ++ks) {
            int k0 = ks * 32 + quad * 8;
            bf16x8 av[2], bv[4];
            #pragma unroll
            for (int it = 0; it < 2; ++it)
                av[it] = ld8(xb + (long)(wave * 32 + it * 16 + col) * 256 + k0);
            #pragma unroll
            for (int nt = 0; nt < 4; ++nt)
                bv[nt] = *(const bf16x8*)(&sm.WT[nt * 16 + col][k0]);
            #pragma unroll
            for (int it = 0; it < 2; ++it)
                #pragma unroll
                for (int nt = 0; nt < 4; ++nt)
                    acc[it][nt] = __builtin_amdgcn_mfma_f32_16x16x32_bf16(av[it], bv[nt], acc[it][nt], 0, 0, 0);
        }
        #pragma unroll
        for (int it = 0; it < 2; ++it)
            #pragma unroll
            for (int nt = 0; nt < 4; ++nt) {
                int f = nt * 16 + col;
                int j = wave * 32 + it * 16 + quad * 4;
                bf16x4 pk = { (__bf16)acc[it][nt][0], (__bf16)acc[it][nt][1],
                              (__bf16)acc[it][nt][2], (__bf16)acc[it][nt][3] };
                *(bf16x4*)(&sm.hT[f][j]) = pk;
            }
    }
    __syncthreads();
    {
        int j = tid & 511;
        float s = 0.f;
        if (tid < 512) {
            #pragma unroll 8
            for (int f = 0; f < 64; ++f) s += (float)sm.hT[f][j] * sm.asrc[f];
            sm.ssrc[j] = s;
        } else {
            #pragma unroll 8
            for (int f = 0; f < 64; ++f) s += (float)sm.hT[f][j] * sm.adst[f];
            sm.sdst[j] = s;
        }
    }
    __syncthreads();
    {
        float si[2];
        const float* arow[2];
        #pragma unroll
        for (int it = 0; it < 2; ++it) {
            int i = wave * 32 + it * 16 + col;
            si[it]   = sm.ssrc[i];
            arow[it] = adj + ((long)b * 512 + i) * 512;
        }
        bf16x8 ones;
        #pragma unroll
        for (int u = 0; u < 8; ++u) ones[u] = (__bf16)1.0f;
        f32x4 acc[2][4] = {};
        f32x4 accs[2]   = {};
        float4 pa0[2], pa1[2];
        #pragma unroll
        for (int it = 0; it < 2; ++it) {
            pa0[it] = *(const float4*)(arow[it] + quad * 8);
            pa1[it] = *(const float4*)(arow[it] + quad * 8 + 4);
        }
        for (int ks = 0; ks < 16; ++ks) {
            int j0 = ks * 32 + quad * 8;
            f32x4 s0 = *(const f32x4*)&sm.sdst[j0];
            f32x4 s1 = *(const f32x4*)&sm.sdst[j0 + 4];
            float sd[8] = {s0[0],s0[1],s0[2],s0[3],s1[0],s1[1],s1[2],s1[3]};
            float am[2][8];
            #pragma unroll
            for (int it = 0; it < 2; ++it) {
                am[it][0]=pa0[it].x; am[it][1]=pa0[it].y;
                am[it][2]=pa0[it].z; am[it][3]=pa0[it].w;
                am[it][4]=pa1[it].x; am[it][5]=pa1[it].y;
                am[it][6]=pa1[it].z; am[it][7]=pa1[it].w;
            }
            if (ks < 15) {
                #pragma unroll
                for (int it = 0; it < 2; ++it) {
                    pa0[it] = *(const float4*)(arow[it] + j0 + 32);
                    pa1[it] = *(const float4*)(arow[it] + j0 + 36);
                }
            }
            bf16x8 P[2];
            #pragma unroll
            for (int it = 0; it < 2; ++it)
                #pragma unroll
                for (int u = 0; u < 8; ++u) {
                    float e = si[it] + sd[u];
                    float l = fmaxf(e, ALPHA * e);
                    float p = am[it][u] * EXP2(l);
                    P[it][u] = (__bf16)p;
                }
            bf16x8 bv[4];
            #pragma unroll
            for (int nt = 0; nt < 4; ++nt)
                bv[nt] = *(const bf16x8*)(&sm.hT[nt * 16 + col][j0]);
            #pragma unroll
            for (int it = 0; it < 2; ++it) {
                #pragma unroll
                for (int nt = 0; nt < 4; ++nt)
                    acc[it][nt] = __builtin_amdgcn_mfma_f32_16x16x32_bf16(P[it], bv[nt], acc[it][nt], 0, 0, 0);
                accs[it] = __builtin_amdgcn_mfma_f32_16x16x32_bf16(P[it], ones, accs[it], 0, 0, 0);
            }
        }
        #pragma unroll
        for (int it = 0; it < 2; ++it)
            #pragma unroll
            for (int r = 0; r < 4; ++r) {
                float s = accs[it][r];
                float inv = (s > 0.f) ? 1.0f / s : 0.f;
                int i = wave * 32 + it * 16 + quad * 4 + r;
                float* orow = out + ((long)b * 512 + i) * 512 + h * 64;
                #pragma unroll
                for (int nt = 0; nt < 4; ++nt)
                    orow[nt * 16 + col] = acc[it][nt][r] * inv;
            }
    }
}

// ---------------- launch ---------------------------------------------------
extern "C" void kernel_launch(void* const* d_in, const int* in_sizes, int n_in,
                              void* d_out, int out_size, void* d_ws, size_t ws_size,
                              hipStream_t stream) {
    const float* x   = (const float*)d_in[0];   // (32,512,256)
    const float* adj = (const float*)d_in[1];   // (32,512,512), {0,1}
    const float* W   = (const float*)d_in[2];   // (256,512)
    const float* a   = (const float*)d_in[3];   // (8,128)
    float* out = (float*)d_out;                 // (32,512,512)

    const size_t HT_BYTES   = 256ull * 2 * 64 * HROW * 2;    // 17,301,504
    const size_t SC_BYTES   = 32ull * 8 * 512 * 4;           //    524,288
    const size_t MASK_BYTES = 32ull * 512 * 64;              //  1,048,576
    const size_t XBF_BYTES  = 32ull * 512 * 256 * 2;         //  8,388,608
    const size_t WBF_BYTES  = 512ull * 256 * 2;              //    262,144
    const size_t NEED = HT_BYTES + 2 * SC_BYTES + MASK_BYTES
                      + XBF_BYTES + WBF_BYTES;               // 28,049,408

    if (d_ws && ws_size >= NEED) {
        char* p = (char*)d_ws;
        __bf16* hT   = (__bf16*)p;                 p += HT_BYTES;
        float* ssrc  = (float*)p;                  p += SC_BYTES;
        float* sdst  = (float*)p;                  p += SC_BYTES;
        unsigned* mk = (unsigned*)p;               p += MASK_BYTES;
        __bf16* xbf  = (__bf16*)p;                 p += XBF_BYTES;
        __bf16* Wbf  = (__bf16*)p;
        k0_all<<<1568, 512, 0, stream>>>(x, W, adj, xbf, Wbf, mk);
        k1_gemm<<<dim3(32, 8, 2), 512, 0, stream>>>(xbf, Wbf, a, hT, ssrc, sdst);
        k2_attn<<<dim3(32, 8, 2), 512, 0, stream>>>((const uint4*)mk, hT, ssrc, sdst, out);
    } else {
        k_gat_fused<<<dim3(32, 8), 1024, 0, stream>>>(x, adj, W, a, out);
    }
}